// Round 9
// baseline (192.631 us; speedup 1.0000x reference)
//
#include <hip/hip_runtime.h>
#include <stdint.h>

// SelfCrossAttn bf16-MFMA pipeline v14. b=4, c=512, N=4096, HEADS=4.
// v14 = v13 (verified 186.1us) + qks/pv FUSION:
//  - gemm_qkv V-epilogue now stores V in PV-B-FRAG-LINEAR layout vTf:
//    elem (e,kk) at ((e>>4)*32+(kk>>5))*512 + (((kk>>3)&3)*16+(e&15))*8+(kk&7)
//  - new `attn` kernel = v13 gemm_qks (QK^T + softmax, unchanged) + P->LDS
//    + register-direct PV (coalesced 1KB B-frags) + yT scatter (2 halves).
//    gemm_pv deleted; P never touches global memory.
// All GEMMs NT: C[m][n] = sum_k A[m][k]*B[n][k], operands k-contiguous.
// STORED row/col order for S/P and vTf cols is kk'' = s*128+t (s = n>>10,
// t = ch&127); semantic attn index is 4t+s.  Sum over kk order-agnostic;
// rows un-permuted only at attn's yT scatter (qsem = (rg&3)*128+4*rl+(rg>>2)).

typedef __attribute__((ext_vector_type(8))) short short8;
typedef __attribute__((ext_vector_type(4))) float f32x4;

typedef const __attribute__((address_space(1))) unsigned int* gas_ptr;
typedef __attribute__((address_space(3))) unsigned int* las_ptr;

#define ATTN_SCALE 0.08838834764831845f   // 128^-0.5

__device__ __forceinline__ unsigned short f2bf(float f) {
    union { float f; unsigned int u; } c; c.f = f;
    unsigned int u = c.u;
    u += 0x7fffu + ((u >> 16) & 1u);      // RNE
    return (unsigned short)(u >> 16);
}

__device__ __forceinline__ void gl_lds16(const void* g, void* l) {
    __builtin_amdgcn_global_load_lds((gas_ptr)(uintptr_t)g, (las_ptr)(uintptr_t)l,
                                     16, 0, 0);
}

// ---- v6 shared MFMA core: 128x128 C-tile, 4 waves, BK=32, 16x16x32 bf16 ----
template<int LDA, int LDB, int KDIM, bool PERMB = false>
__device__ __forceinline__ void mfma_core(
    const unsigned short* __restrict__ A,
    const unsigned short* __restrict__ B,
    int m0, int n0,
    unsigned short* __restrict__ sA, unsigned short* __restrict__ sB,
    f32x4 acc[4][4])
{
    const int tid  = threadIdx.x;
    const int lane = tid & 63, wave = tid >> 6;
    const int lr = lane >> 2, lc = lane & 3;       // staging: 16 rows x 4 chunks
    const int lcs = lc ^ ((lr >> 1) & 3);          // source-chunk swizzle
    const int wm = (wave & 1) * 64, wn = (wave >> 1) * 64;
    const int col = lane & 15, quad = lane >> 4;
    const int swz = (quad ^ ((col >> 1) & 3)) * 8; // read-side swizzle (shorts)

    const unsigned short* ga = A + (size_t)(m0 + 32 * wave + lr) * LDA + lcs * 8;
    int rb0 = n0 + 32 * wave + lr;
    int rb1 = rb0 + 16;
    if (PERMB) {
        rb0 = 4 * (rb0 & 127) + (rb0 >> 7);
        rb1 = 4 * (rb1 & 127) + (rb1 >> 7);
    }
    const unsigned short* gb0 = B + (size_t)rb0 * LDB + lcs * 8;
    const unsigned short* gb1 = B + (size_t)rb1 * LDB + lcs * 8;

    const int wr0 = (32 * wave) * 32;              // wave-uniform LDS row bases
    const int wr1 = (32 * wave + 16) * 32;

    // prologue: stage K-step 0 into buffer 0
    gl_lds16(ga,            sA + wr0);
    gl_lds16(ga + 16 * LDA, sA + wr1);
    gl_lds16(gb0,           sB + wr0);
    gl_lds16(gb1,           sB + wr1);

    constexpr int NK = KDIM / 32;
    for (int kk = 0; kk < NK; ++kk) {
        const int bo = (kk & 1) * 4096;
        if (kk + 1 < NK) {
            const int nb = ((kk + 1) & 1) * 4096;
            const int k0 = (kk + 1) * 32;
            gl_lds16(ga + k0,            sA + nb + wr0);
            gl_lds16(ga + k0 + 16 * LDA, sA + nb + wr1);
            gl_lds16(gb0 + k0,           sB + nb + wr0);
            gl_lds16(gb1 + k0,           sB + nb + wr1);
            asm volatile("s_waitcnt vmcnt(4)" ::: "memory");
        } else {
            asm volatile("s_waitcnt vmcnt(0)" ::: "memory");
        }
        __builtin_amdgcn_s_barrier();
        asm volatile("" ::: "memory");
        __builtin_amdgcn_sched_barrier(0);

        const unsigned short* bA = sA + bo;
        const unsigned short* bB = sB + bo;
        short8 af[4], bfv[4];
        #pragma unroll
        for (int i = 0; i < 4; ++i)
            af[i] = *(const short8*)&bA[(wm + i * 16 + col) * 32 + swz];
        #pragma unroll
        for (int j = 0; j < 4; ++j)
            bfv[j] = *(const short8*)&bB[(wn + j * 16 + col) * 32 + swz];
        #pragma unroll
        for (int i = 0; i < 4; ++i)
            #pragma unroll
            for (int j = 0; j < 4; ++j)
                acc[i][j] = __builtin_amdgcn_mfma_f32_16x16x32_bf16(
                    af[i], bfv[j], acc[i][j], 0, 0, 0);

        __builtin_amdgcn_s_barrier();          // reads done before next stage
        asm volatile("" ::: "memory");
    }
}

// ---- prep: z<4 -> transpose x[b][c][n]->xT[b][n][c] bf16 ; z==4 -> W conv ----
__global__ __launch_bounds__(256)
void prep(const float* __restrict__ x,
          const float* __restrict__ Wq, const float* __restrict__ Wk,
          const float* __restrict__ Wv, const float* __restrict__ Wp,
          unsigned short* __restrict__ xT, unsigned short* __restrict__ Wb)
{
    if (blockIdx.z == 4) {
        const int idx = (blockIdx.y * 64 + blockIdx.x) * 256 + threadIdx.x; // 262144
        const int mat = idx >> 16;
        const int off = (idx & 65535) << 2;
        const float* src = (mat == 0 ? Wq : mat == 1 ? Wk : mat == 2 ? Wv : Wp) + off;
        const float4 f = *(const float4*)src;
        uint2 o;
        o.x = f2bf(f.x) | ((unsigned)f2bf(f.y) << 16);
        o.y = f2bf(f.z) | ((unsigned)f2bf(f.w) << 16);
        *(uint2*)&Wb[mat * 262144 + off] = o;
        return;
    }
    const int b = blockIdx.z;
    const int l = threadIdx.x & 63, w = threadIdx.x >> 6;
    const int n  = blockIdx.x * 64 + l;
    const int c0 = blockIdx.y * 32 + w * 8;
    const float* xp = x + (size_t)b * 2097152 + (size_t)c0 * 4096 + n;
    unsigned int p[4];
    #pragma unroll
    for (int j = 0; j < 4; ++j) {
        const unsigned short a  = f2bf(xp[(2 * j)     * 4096]);
        const unsigned short bb = f2bf(xp[(2 * j + 1) * 4096]);
        p[j] = a | ((unsigned)bb << 16);
    }
    uint4 v; v.x = p[0]; v.y = p[1]; v.z = p[2]; v.w = p[3];
    *(uint4*)&xT[(size_t)b * 2097152 + (size_t)n * 512 + c0] = v;
}

// ---- K1: q/k = W @ x -> frag-linear (stored rows); V -> vTf frag-linear ----
__global__ __launch_bounds__(256)
void gemm_qkv(const unsigned short* __restrict__ Wb,
              const unsigned short* __restrict__ xT,
              unsigned short* __restrict__ qb, unsigned short* __restrict__ kb,
              unsigned short* __restrict__ vT)
{
    __shared__ unsigned short sT[128 * 136];          // 34.8 KB, aliases staging
    unsigned short* sA = sT;                          // [2][128*32] = 8192
    unsigned short* sB = sT + 8192;                   // [2][128*32] = 8192

    const int z = blockIdx.z, wsel = z >> 2, b = z & 3;
    const unsigned short* A = Wb + wsel * 262144;
    const unsigned short* B = xT + (size_t)b * 2097152;
    const int m0 = blockIdx.y * 128, n0 = blockIdx.x * 128;

    f32x4 z4 = {0.f, 0.f, 0.f, 0.f};
    f32x4 acc[4][4];
    #pragma unroll
    for (int i = 0; i < 4; ++i)
        #pragma unroll
        for (int j = 0; j < 4; ++j) acc[i][j] = z4;

    mfma_core<512, 512, 512>(A, B, m0, n0, sA, sB, acc);

    __syncthreads();   // drain before overwriting aliased staging

    const int tid = threadIdx.x;
    const int lane = tid & 63, wave = tid >> 6;
    const int wm = (wave & 1) * 64, wn = (wave >> 1) * 64;
    const int col = lane & 15, quad = lane >> 4;
    const int h = m0 >> 7, s = n0 >> 10;

    if (wsel < 2) {
        // stage C-tile [rr][ee], pad 136
        #pragma unroll
        for (int i = 0; i < 4; ++i)
            #pragma unroll
            for (int r = 0; r < 4; ++r) {
                const int rr = wm + i * 16 + quad * 4 + r;
                #pragma unroll
                for (int j = 0; j < 4; ++j)
                    sT[rr * 136 + wn + j * 16 + col] = f2bf(acc[i][j][r]);
            }
        __syncthreads();
        // frag-linear: stored_row = s*128 + t (t = rr); for elem (t, e):
        // addr = ((s*8 + t>>4)*32 + e>>5)*512 + (((e>>3)&3)*16 + (t&15))*8 + (e&7)
        unsigned short* C = (wsel == 0 ? qb : kb)
                          + (size_t)(b * 4 + h) * 524288;
        const int bKc = (n0 & 1023) >> 5;
        const int u = tid & 15, v = (tid >> 4) & 3, wv = tid >> 6;
        unsigned short* dst = C + (size_t)(s * 256 + bKc + wv) * 512
                            + (v * 16 + u) * 8;
        const unsigned short* src = sT + u * 136 + wv * 32 + v * 8;
        #pragma unroll
        for (int k = 0; k < 8; ++k)
            *(uint4*)(dst + k * 16384) = *(const uint4*)(src + k * 2176);
    } else {
        // stage transposed [ee][rr] (vT col kk'' = s*128 + rr), pad 136
        #pragma unroll
        for (int i = 0; i < 4; ++i)
            #pragma unroll
            for (int r = 0; r < 4; ++r) {
                const int rr = wm + i * 16 + quad * 4 + r;
                #pragma unroll
                for (int j = 0; j < 4; ++j)
                    sT[(wn + j * 16 + col) * 136 + rr] = f2bf(acc[i][j][r]);
            }
        __syncthreads();
        // vTf frag-linear: elem (e,kk) at ((e>>4)*32 + kk>>5)*512
        //   + (((kk>>3)&3)*16 + (e&15))*8 + (kk&7);  e = e0+ee, kk = s*128+rr.
        // Thread (ce = tid&15, j = tid>>4 = Kcl*4+qc): 8 uint4 over Re=ee>>4.
        const int e0 = n0 & 1023;
        unsigned short* dstb = vT + (size_t)(b * 4 + h) * 524288;
        const int ce = tid & 15, j = tid >> 4;
        const size_t base = (size_t)((e0 >> 4) * 32 + s * 4 + (j >> 2)) * 512
                          + ((j & 3) * 16 + ce) * 8;
        const unsigned short* srcb = sT + ce * 136 + j * 8;
        #pragma unroll
        for (int Re = 0; Re < 8; ++Re)
            *(uint4*)&dstb[base + (size_t)Re * 16384]
                = *(const uint4*)&srcb[Re * 2176];
    }
}

// ---- K2 v14: fused attn: S=Q.K^T + softmax + O=P.V' + yT scatter ----
// 256 blocks x 512 threads; block = 32 stored rows (rg) x full slab.
// QK/softmax identical to v13's verified gemm_qks; P kept in LDS Pl[32][520];
// PV register-direct (A from Pl, B = coalesced vTf frags); O staged+scattered
// in 2 halves aliased on Pl.
__global__ __launch_bounds__(512)
void attn(const unsigned short* __restrict__ qb,
          const unsigned short* __restrict__ kb,
          const unsigned short* __restrict__ vTf,
          unsigned short* __restrict__ yT)
{
    __shared__ unsigned short Pl[32 * 520];           // 33,280 B (P, then O)
    __shared__ float red[2][32][8];
    const int d = blockIdx.x;                         // 0..255
    const int flat = (d & 7) * 32 + (d >> 3);         // XCD-chunked remap
    const int rg = flat & 15, z = flat >> 4;          // row-group, slab
    const int b = z >> 2, hh = z & 3;
    const unsigned short* Aq = qb + (size_t)z * 524288;
    const unsigned short* Bk = kb + (size_t)z * 524288;
    const unsigned short* Vz = vTf + (size_t)z * 524288;
    unsigned short* yTb = yT + (size_t)b * 2097152;

    const int tid = threadIdx.x;
    const int lane = tid & 63, w = tid >> 6;
    const int col = lane & 15, quad = lane >> 4;

    // ---- QK^T (v13 gemm_qks, verified) ----
    const unsigned short* ap0 = Aq + (size_t)((rg * 2 + 0) * 32) * 512 + lane * 8;
    const unsigned short* ap1 = Aq + (size_t)((rg * 2 + 1) * 32) * 512 + lane * 8;
    const unsigned short* bp0 = Bk + (size_t)((w * 4 + 0) * 32) * 512 + lane * 8;
    const unsigned short* bp1 = bp0 + 16384;
    const unsigned short* bp2 = bp0 + 32768;
    const unsigned short* bp3 = bp0 + 49152;

    f32x4 z4 = {0.f, 0.f, 0.f, 0.f};
    f32x4 acc[2][4];
    #pragma unroll
    for (int f = 0; f < 2; ++f)
        #pragma unroll
        for (int g = 0; g < 4; ++g) acc[f][g] = z4;

    #pragma unroll 4
    for (int kk = 0; kk < 32; ++kk) {
        const int o = kk * 512;
        const short8 af0 = *(const short8*)(ap0 + o);
        const short8 af1 = *(const short8*)(ap1 + o);
        short8 bf[4];
        bf[0] = *(const short8*)(bp0 + o);
        bf[1] = *(const short8*)(bp1 + o);
        bf[2] = *(const short8*)(bp2 + o);
        bf[3] = *(const short8*)(bp3 + o);
        #pragma unroll
        for (int g = 0; g < 4; ++g)
            acc[0][g] = __builtin_amdgcn_mfma_f32_16x16x32_bf16(
                af0, bf[g], acc[0][g], 0, 0, 0);
        #pragma unroll
        for (int g = 0; g < 4; ++g)
            acc[1][g] = __builtin_amdgcn_mfma_f32_16x16x32_bf16(
                af1, bf[g], acc[1][g], 0, 0, 0);
    }

    // ---- softmax over full 512-wide rows -> Pl (bf16) ----
    float mx[2][4];
    #pragma unroll
    for (int f = 0; f < 2; ++f)
        #pragma unroll
        for (int r = 0; r < 4; ++r) {
            float m = acc[f][0][r];
            #pragma unroll
            for (int g = 1; g < 4; ++g) m = fmaxf(m, acc[f][g][r]);
            #pragma unroll
            for (int s = 1; s < 16; s <<= 1) m = fmaxf(m, __shfl_xor(m, s));
            mx[f][r] = m;
        }
    if (col == 0) {
        #pragma unroll
        for (int f = 0; f < 2; ++f)
            #pragma unroll
            for (int r = 0; r < 4; ++r)
                red[0][f * 16 + quad * 4 + r][w] = mx[f][r];
    }
    __syncthreads();
    float sm[2][4];
    #pragma unroll
    for (int f = 0; f < 2; ++f)
        #pragma unroll
        for (int r = 0; r < 4; ++r) {
            const int row = f * 16 + quad * 4 + r;
            float m = red[0][row][0];
            #pragma unroll
            for (int t = 1; t < 8; ++t) m = fmaxf(m, red[0][row][t]);
            float s = 0.f;
            #pragma unroll
            for (int g = 0; g < 4; ++g) {
                const float e = __expf((acc[f][g][r] - m) * ATTN_SCALE);
                acc[f][g][r] = e;
                s += e;
            }
            #pragma unroll
            for (int t = 1; t < 16; t <<= 1) s += __shfl_xor(s, t);
            sm[f][r] = s;
        }
    if (col == 0) {
        #pragma unroll
        for (int f = 0; f < 2; ++f)
            #pragma unroll
            for (int r = 0; r < 4; ++r)
                red[1][f * 16 + quad * 4 + r][w] = sm[f][r];
    }
    __syncthreads();
    #pragma unroll
    for (int f = 0; f < 2; ++f)
        #pragma unroll
        for (int r = 0; r < 4; ++r) {
            const int row = f * 16 + quad * 4 + r;
            float tot = red[1][row][0];
            #pragma unroll
            for (int t = 1; t < 8; ++t) tot += red[1][row][t];
            const float inv = 1.f / tot;
            #pragma unroll
            for (int g = 0; g < 4; ++g)
                Pl[row * 520 + w * 64 + g * 16 + col] =
                    f2bf(acc[f][g][r] * inv);
        }
    __syncthreads();   // Pl complete

    // ---- PV: out[32][1024] = P . V' ; wave w owns e = w*128..+128 ----
    f32x4 accp[2][8];
    #pragma unroll
    for (int f = 0; f < 2; ++f)
        #pragma unroll
        for (int g2 = 0; g2 < 8; ++g2) accp[f][g2] = z4;

    #pragma unroll 2
    for (int Kc = 0; Kc < 16; ++Kc) {
        const short8 a0 = *(const short8*)&Pl[col * 520 + Kc * 32 + quad * 8];
        const short8 a1 = *(const short8*)&Pl[(16 + col) * 520 + Kc * 32 + quad * 8];
        short8 bv[8];
        #pragma unroll
        for (int g2 = 0; g2 < 8; ++g2)
            bv[g2] = *(const short8*)&Vz[(size_t)((w * 8 + g2) * 32 + Kc) * 512
                                         + lane * 8];
        #pragma unroll
        for (int g2 = 0; g2 < 8; ++g2) {
            accp[0][g2] = __builtin_amdgcn_mfma_f32_16x16x32_bf16(
                a0, bv[g2], accp[0][g2], 0, 0, 0);
            accp[1][g2] = __builtin_amdgcn_mfma_f32_16x16x32_bf16(
                a1, bv[g2], accp[1][g2], 0, 0, 0);
        }
    }
    __syncthreads();   // done reading Pl; safe to overwrite as Ol

    // ---- epilogue: 2 halves (e<512 by waves 0-3, e>=512 by waves 4-7) ----
    // yT[n][cdim]: n = (e&7)*512 + qsem, cdim = hh*128 + (e>>3);
    // qsem = (rg&3)*128 + 4*rl + (rg>>2)   (stored-row un-permute)
    unsigned short* Ol = Pl;
    const int rl = tid >> 4, s8 = (tid >> 1) & 7, hw = tid & 1;
    const int qsem = ((rg & 3) << 7) + 4 * rl + (rg >> 2);
    const size_t nbase = (size_t)(s8 * 512 + qsem) * 512 + hh * 128;
    #pragma unroll
    for (int h2 = 0; h2 < 2; ++h2) {
        if ((w >> 2) == h2) {
            const int wl = w & 3;
            #pragma unroll
            for (int f = 0; f < 2; ++f)
                #pragma unroll
                for (int g2 = 0; g2 < 8; ++g2)
                    #pragma unroll
                    for (int r = 0; r < 4; ++r)
                        Ol[(f * 16 + quad * 4 + r) * 520
                           + wl * 128 + g2 * 16 + col] = f2bf(accp[f][g2][r]);
        }
        __syncthreads();
        #pragma unroll
        for (int v2 = 0; v2 < 4; ++v2) {
            const int cdb = hw * 32 + v2 * 8;
            unsigned int p[4];
            #pragma unroll
            for (int t = 0; t < 4; ++t) {
                const unsigned int a  = Ol[rl * 520 + s8 + 8 * (cdb + 2 * t)];
                const unsigned int bb = Ol[rl * 520 + s8 + 8 * (cdb + 2 * t + 1)];
                p[t] = a | (bb << 16);
            }
            uint4 o; o.x = p[0]; o.y = p[1]; o.z = p[2]; o.w = p[3];
            *(uint4*)&yTb[nbase + h2 * 64 + cdb] = o;
        }
        __syncthreads();
    }
}

// ---- K5: out = Wproj @ y + bias + x (NT vs yT), fp32 out ----
__global__ __launch_bounds__(256)
void gemm_proj(const unsigned short* __restrict__ Wpb,
               const unsigned short* __restrict__ yT,
               const float* __restrict__ bias, const float* __restrict__ x,
               float* __restrict__ out)
{
    __shared__ unsigned short sA[2 * 128 * 32], sB[2 * 128 * 32];
    const int b = blockIdx.z;
    const unsigned short* B = yT + (size_t)b * 2097152;  // [4096][512]
    const int m0 = blockIdx.y * 128, n0 = blockIdx.x * 128;

    f32x4 z4 = {0.f, 0.f, 0.f, 0.f};
    f32x4 acc[4][4];
    #pragma unroll
    for (int i = 0; i < 4; ++i)
        #pragma unroll
        for (int j = 0; j < 4; ++j) acc[i][j] = z4;

    mfma_core<512, 512, 512>(Wpb, B, m0, n0, sA, sB, acc);

    const int lane = threadIdx.x & 63, wave = threadIdx.x >> 6;
    const int wm = (wave & 1) * 64, wn = (wave >> 1) * 64;
    const int col = lane & 15, quad = lane >> 4;
    const size_t boff = (size_t)b * 2097152;
    #pragma unroll
    for (int i = 0; i < 4; ++i)
        #pragma unroll
        for (int r = 0; r < 4; ++r) {
            const int row = m0 + wm + i * 16 + quad * 4 + r;
            const float bi = bias[row];
            #pragma unroll
            for (int j = 0; j < 4; ++j) {
                const size_t idx = boff + (size_t)row * 4096 + n0 + wn + j * 16 + col;
                out[idx] = acc[i][j][r] + bi + x[idx];
            }
        }
}

extern "C" void kernel_launch(void* const* d_in, const int* in_sizes, int n_in,
                              void* d_out, int out_size, void* d_ws, size_t ws_size,
                              hipStream_t stream) {
    const float* x     = (const float*)d_in[0];
    const float* Wq    = (const float*)d_in[1];
    const float* Wk    = (const float*)d_in[2];
    const float* Wv    = (const float*)d_in[3];
    const float* Wproj = (const float*)d_in[4];
    const float* bproj = (const float*)d_in[5];
    float* out = (float*)d_out;

    char* w = (char*)d_ws;
    unsigned short* xT = (unsigned short*)(w + 0);          // 16 MB [b][n][c]
    unsigned short* qb = (unsigned short*)(w + 16777216);   // 16 MB frag-layout
    unsigned short* kb = (unsigned short*)(w + 33554432);   // 16 MB frag-layout
    unsigned short* vT = (unsigned short*)(w + 50331648);   // 16 MB frag-layout
    unsigned short* Wb = (unsigned short*)(w + 109051904);  //  2 MB
    unsigned short* yT = xT;   // xT dead after gemm_qkv

    prep        <<<dim3(64, 16, 5),  256, 0, stream>>>(x, Wq, Wk, Wv, Wproj, xT, Wb);
    gemm_qkv    <<<dim3(32, 4, 12),  256, 0, stream>>>(Wb, xT, qb, kb, vT);
    attn        <<<dim3(256),        512, 0, stream>>>(qb, kb, vT, yT);
    gemm_proj   <<<dim3(32, 4, 4),   256, 0, stream>>>(Wb + 3 * 262144, yT, bproj, x, out);
}

// Round 10
// 189.238 us; speedup vs baseline: 1.0179x; 1.0179x over previous
//
#include <hip/hip_runtime.h>
#include <stdint.h>

// SelfCrossAttn bf16-MFMA pipeline v15. b=4, c=512, N=4096, HEADS=4.
// v15 = v14 + attn-internal fixes only:
//  (1) Q staged once to LDS (64KB, frag-linear) -> QK global loads 6->4/iter
//  (2) P stored frag-linear in LDS -> PV A-reads lane-linear, conflict-free
//  (3) PV software-pipelined: V prefetch issued before softmax; bvA/bvB dbuf
// All GEMMs NT: C[m][n] = sum_k A[m][k]*B[n][k], operands k-contiguous.
// STORED row/col order for S/P and vTf cols is kk'' = s*128+t (s = n>>10,
// t = ch&127); semantic attn index is 4t+s.  Sum over kk order-agnostic;
// rows un-permuted only at attn's yT scatter (qsem = (rg&3)*128+4*rl+(rg>>2)).

typedef __attribute__((ext_vector_type(8))) short short8;
typedef __attribute__((ext_vector_type(4))) float f32x4;

typedef const __attribute__((address_space(1))) unsigned int* gas_ptr;
typedef __attribute__((address_space(3))) unsigned int* las_ptr;

#define ATTN_SCALE 0.08838834764831845f   // 128^-0.5

__device__ __forceinline__ unsigned short f2bf(float f) {
    union { float f; unsigned int u; } c; c.f = f;
    unsigned int u = c.u;
    u += 0x7fffu + ((u >> 16) & 1u);      // RNE
    return (unsigned short)(u >> 16);
}

__device__ __forceinline__ void gl_lds16(const void* g, void* l) {
    __builtin_amdgcn_global_load_lds((gas_ptr)(uintptr_t)g, (las_ptr)(uintptr_t)l,
                                     16, 0, 0);
}

// ---- v6 shared MFMA core: 128x128 C-tile, 4 waves, BK=32, 16x16x32 bf16 ----
template<int LDA, int LDB, int KDIM, bool PERMB = false>
__device__ __forceinline__ void mfma_core(
    const unsigned short* __restrict__ A,
    const unsigned short* __restrict__ B,
    int m0, int n0,
    unsigned short* __restrict__ sA, unsigned short* __restrict__ sB,
    f32x4 acc[4][4])
{
    const int tid  = threadIdx.x;
    const int lane = tid & 63, wave = tid >> 6;
    const int lr = lane >> 2, lc = lane & 3;       // staging: 16 rows x 4 chunks
    const int lcs = lc ^ ((lr >> 1) & 3);          // source-chunk swizzle
    const int wm = (wave & 1) * 64, wn = (wave >> 1) * 64;
    const int col = lane & 15, quad = lane >> 4;
    const int swz = (quad ^ ((col >> 1) & 3)) * 8; // read-side swizzle (shorts)

    const unsigned short* ga = A + (size_t)(m0 + 32 * wave + lr) * LDA + lcs * 8;
    int rb0 = n0 + 32 * wave + lr;
    int rb1 = rb0 + 16;
    if (PERMB) {
        rb0 = 4 * (rb0 & 127) + (rb0 >> 7);
        rb1 = 4 * (rb1 & 127) + (rb1 >> 7);
    }
    const unsigned short* gb0 = B + (size_t)rb0 * LDB + lcs * 8;
    const unsigned short* gb1 = B + (size_t)rb1 * LDB + lcs * 8;

    const int wr0 = (32 * wave) * 32;              // wave-uniform LDS row bases
    const int wr1 = (32 * wave + 16) * 32;

    // prologue: stage K-step 0 into buffer 0
    gl_lds16(ga,            sA + wr0);
    gl_lds16(ga + 16 * LDA, sA + wr1);
    gl_lds16(gb0,           sB + wr0);
    gl_lds16(gb1,           sB + wr1);

    constexpr int NK = KDIM / 32;
    for (int kk = 0; kk < NK; ++kk) {
        const int bo = (kk & 1) * 4096;
        if (kk + 1 < NK) {
            const int nb = ((kk + 1) & 1) * 4096;
            const int k0 = (kk + 1) * 32;
            gl_lds16(ga + k0,            sA + nb + wr0);
            gl_lds16(ga + k0 + 16 * LDA, sA + nb + wr1);
            gl_lds16(gb0 + k0,           sB + nb + wr0);
            gl_lds16(gb1 + k0,           sB + nb + wr1);
            asm volatile("s_waitcnt vmcnt(4)" ::: "memory");
        } else {
            asm volatile("s_waitcnt vmcnt(0)" ::: "memory");
        }
        __builtin_amdgcn_s_barrier();
        asm volatile("" ::: "memory");
        __builtin_amdgcn_sched_barrier(0);

        const unsigned short* bA = sA + bo;
        const unsigned short* bB = sB + bo;
        short8 af[4], bfv[4];
        #pragma unroll
        for (int i = 0; i < 4; ++i)
            af[i] = *(const short8*)&bA[(wm + i * 16 + col) * 32 + swz];
        #pragma unroll
        for (int j = 0; j < 4; ++j)
            bfv[j] = *(const short8*)&bB[(wn + j * 16 + col) * 32 + swz];
        #pragma unroll
        for (int i = 0; i < 4; ++i)
            #pragma unroll
            for (int j = 0; j < 4; ++j)
                acc[i][j] = __builtin_amdgcn_mfma_f32_16x16x32_bf16(
                    af[i], bfv[j], acc[i][j], 0, 0, 0);

        __builtin_amdgcn_s_barrier();          // reads done before next stage
        asm volatile("" ::: "memory");
    }
}

// ---- prep: z<4 -> transpose x[b][c][n]->xT[b][n][c] bf16 ; z==4 -> W conv ----
__global__ __launch_bounds__(256)
void prep(const float* __restrict__ x,
          const float* __restrict__ Wq, const float* __restrict__ Wk,
          const float* __restrict__ Wv, const float* __restrict__ Wp,
          unsigned short* __restrict__ xT, unsigned short* __restrict__ Wb)
{
    if (blockIdx.z == 4) {
        const int idx = (blockIdx.y * 64 + blockIdx.x) * 256 + threadIdx.x; // 262144
        const int mat = idx >> 16;
        const int off = (idx & 65535) << 2;
        const float* src = (mat == 0 ? Wq : mat == 1 ? Wk : mat == 2 ? Wv : Wp) + off;
        const float4 f = *(const float4*)src;
        uint2 o;
        o.x = f2bf(f.x) | ((unsigned)f2bf(f.y) << 16);
        o.y = f2bf(f.z) | ((unsigned)f2bf(f.w) << 16);
        *(uint2*)&Wb[mat * 262144 + off] = o;
        return;
    }
    const int b = blockIdx.z;
    const int l = threadIdx.x & 63, w = threadIdx.x >> 6;
    const int n  = blockIdx.x * 64 + l;
    const int c0 = blockIdx.y * 32 + w * 8;
    const float* xp = x + (size_t)b * 2097152 + (size_t)c0 * 4096 + n;
    unsigned int p[4];
    #pragma unroll
    for (int j = 0; j < 4; ++j) {
        const unsigned short a  = f2bf(xp[(2 * j)     * 4096]);
        const unsigned short bb = f2bf(xp[(2 * j + 1) * 4096]);
        p[j] = a | ((unsigned)bb << 16);
    }
    uint4 v; v.x = p[0]; v.y = p[1]; v.z = p[2]; v.w = p[3];
    *(uint4*)&xT[(size_t)b * 2097152 + (size_t)n * 512 + c0] = v;
}

// ---- K1: q/k = W @ x -> frag-linear (stored rows); V -> vTf frag-linear ----
__global__ __launch_bounds__(256)
void gemm_qkv(const unsigned short* __restrict__ Wb,
              const unsigned short* __restrict__ xT,
              unsigned short* __restrict__ qb, unsigned short* __restrict__ kb,
              unsigned short* __restrict__ vT)
{
    __shared__ unsigned short sT[128 * 136];          // 34.8 KB, aliases staging
    unsigned short* sA = sT;                          // [2][128*32] = 8192
    unsigned short* sB = sT + 8192;                   // [2][128*32] = 8192

    const int z = blockIdx.z, wsel = z >> 2, b = z & 3;
    const unsigned short* A = Wb + wsel * 262144;
    const unsigned short* B = xT + (size_t)b * 2097152;
    const int m0 = blockIdx.y * 128, n0 = blockIdx.x * 128;

    f32x4 z4 = {0.f, 0.f, 0.f, 0.f};
    f32x4 acc[4][4];
    #pragma unroll
    for (int i = 0; i < 4; ++i)
        #pragma unroll
        for (int j = 0; j < 4; ++j) acc[i][j] = z4;

    mfma_core<512, 512, 512>(A, B, m0, n0, sA, sB, acc);

    __syncthreads();   // drain before overwriting aliased staging

    const int tid = threadIdx.x;
    const int lane = tid & 63, wave = tid >> 6;
    const int wm = (wave & 1) * 64, wn = (wave >> 1) * 64;
    const int col = lane & 15, quad = lane >> 4;
    const int h = m0 >> 7, s = n0 >> 10;

    if (wsel < 2) {
        // stage C-tile [rr][ee], pad 136
        #pragma unroll
        for (int i = 0; i < 4; ++i)
            #pragma unroll
            for (int r = 0; r < 4; ++r) {
                const int rr = wm + i * 16 + quad * 4 + r;
                #pragma unroll
                for (int j = 0; j < 4; ++j)
                    sT[rr * 136 + wn + j * 16 + col] = f2bf(acc[i][j][r]);
            }
        __syncthreads();
        // frag-linear: stored_row = s*128 + t (t = rr); for elem (t, e):
        // addr = ((s*8 + t>>4)*32 + e>>5)*512 + (((e>>3)&3)*16 + (t&15))*8 + (e&7)
        unsigned short* C = (wsel == 0 ? qb : kb)
                          + (size_t)(b * 4 + h) * 524288;
        const int bKc = (n0 & 1023) >> 5;
        const int u = tid & 15, v = (tid >> 4) & 3, wv = tid >> 6;
        unsigned short* dst = C + (size_t)(s * 256 + bKc + wv) * 512
                            + (v * 16 + u) * 8;
        const unsigned short* src = sT + u * 136 + wv * 32 + v * 8;
        #pragma unroll
        for (int k = 0; k < 8; ++k)
            *(uint4*)(dst + k * 16384) = *(const uint4*)(src + k * 2176);
    } else {
        // stage transposed [ee][rr] (vT col kk'' = s*128 + rr), pad 136
        #pragma unroll
        for (int i = 0; i < 4; ++i)
            #pragma unroll
            for (int r = 0; r < 4; ++r) {
                const int rr = wm + i * 16 + quad * 4 + r;
                #pragma unroll
                for (int j = 0; j < 4; ++j)
                    sT[(wn + j * 16 + col) * 136 + rr] = f2bf(acc[i][j][r]);
            }
        __syncthreads();
        // vTf frag-linear: elem (e,kk) at ((e>>4)*32 + kk>>5)*512
        //   + (((kk>>3)&3)*16 + (e&15))*8 + (kk&7);  e = e0+ee, kk = s*128+rr.
        const int e0 = n0 & 1023;
        unsigned short* dstb = vT + (size_t)(b * 4 + h) * 524288;
        const int ce = tid & 15, j = tid >> 4;
        const size_t base = (size_t)((e0 >> 4) * 32 + s * 4 + (j >> 2)) * 512
                          + ((j & 3) * 16 + ce) * 8;
        const unsigned short* srcb = sT + ce * 136 + j * 8;
        #pragma unroll
        for (int Re = 0; Re < 8; ++Re)
            *(uint4*)&dstb[base + (size_t)Re * 16384]
                = *(const uint4*)&srcb[Re * 2176];
    }
}

// ---- K2 v15: fused attn: S=Q.K^T + softmax + O=P.V' + yT scatter ----
// 256 blocks x 512 threads; block = 32 stored rows (rg) x full slab.
// Q staged to LDS once (frag-linear, conflict-free reads); P frag-linear in
// LDS; PV double-buffered with V prefetch issued before softmax.
__global__ __launch_bounds__(512)
void attn(const unsigned short* __restrict__ qb,
          const unsigned short* __restrict__ kb,
          const unsigned short* __restrict__ vTf,
          unsigned short* __restrict__ yT)
{
    __shared__ unsigned short sAq[32 * 1024];         // 64 KB staged Q
    __shared__ unsigned short Pl[16640];              // P frag (32KB) / O[32][520]
    __shared__ float red[2][32][8];
    const int d = blockIdx.x;                         // 0..255
    const int flat = (d & 7) * 32 + (d >> 3);         // XCD-chunked remap
    const int rg = flat & 15, z = flat >> 4;          // row-group, slab
    const int b = z >> 2, hh = z & 3;
    const unsigned short* Aq = qb + (size_t)z * 524288;
    const unsigned short* Bk = kb + (size_t)z * 524288;
    const unsigned short* Vz = vTf + (size_t)z * 524288;
    unsigned short* yTb = yT + (size_t)b * 2097152;

    const int tid = threadIdx.x;
    const int lane = tid & 63, w = tid >> 6;
    const int col = lane & 15, quad = lane >> 4;

    // ---- stage Q (2 frag-rows = 64 KB, already frag-linear in qb) ----
    {
        const unsigned short* gsrc = Aq + (size_t)(rg * 2 * 32) * 512 + lane * 8;
        #pragma unroll
        for (int i = 0; i < 8; ++i)
            gl_lds16(gsrc + (i * 8 + w) * 512, sAq + (i * 8 + w) * 512);
    }

    const unsigned short* bp0 = Bk + (size_t)((w * 4 + 0) * 32) * 512 + lane * 8;
    const unsigned short* bp1 = bp0 + 16384;
    const unsigned short* bp2 = bp0 + 32768;
    const unsigned short* bp3 = bp0 + 49152;

    asm volatile("s_waitcnt vmcnt(0)" ::: "memory");
    __builtin_amdgcn_s_barrier();
    asm volatile("" ::: "memory");

    // ---- QK^T: A from LDS (conflict-free), B register-direct ----
    f32x4 z4 = {0.f, 0.f, 0.f, 0.f};
    f32x4 acc[2][4];
    #pragma unroll
    for (int f = 0; f < 2; ++f)
        #pragma unroll
        for (int g = 0; g < 4; ++g) acc[f][g] = z4;

    #pragma unroll 4
    for (int kk = 0; kk < 32; ++kk) {
        const int o = kk * 512;
        const short8 af0 = *(const short8*)&sAq[o + lane * 8];
        const short8 af1 = *(const short8*)&sAq[16384 + o + lane * 8];
        short8 bf[4];
        bf[0] = *(const short8*)(bp0 + o);
        bf[1] = *(const short8*)(bp1 + o);
        bf[2] = *(const short8*)(bp2 + o);
        bf[3] = *(const short8*)(bp3 + o);
        #pragma unroll
        for (int g = 0; g < 4; ++g)
            acc[0][g] = __builtin_amdgcn_mfma_f32_16x16x32_bf16(
                af0, bf[g], acc[0][g], 0, 0, 0);
        #pragma unroll
        for (int g = 0; g < 4; ++g)
            acc[1][g] = __builtin_amdgcn_mfma_f32_16x16x32_bf16(
                af1, bf[g], acc[1][g], 0, 0, 0);
    }

    // ---- issue V prefetch for Kc=0 (completes under softmax) ----
    short8 bvA[8], bvB[8];
    #pragma unroll
    for (int g2 = 0; g2 < 8; ++g2)
        bvA[g2] = *(const short8*)&Vz[(size_t)((w * 8 + g2) * 32) * 512 + lane * 8];

    // ---- softmax over full 512-wide rows -> Pl (frag-linear bf16) ----
    float mx[2][4];
    #pragma unroll
    for (int f = 0; f < 2; ++f)
        #pragma unroll
        for (int r = 0; r < 4; ++r) {
            float m = acc[f][0][r];
            #pragma unroll
            for (int g = 1; g < 4; ++g) m = fmaxf(m, acc[f][g][r]);
            #pragma unroll
            for (int s = 1; s < 16; s <<= 1) m = fmaxf(m, __shfl_xor(m, s));
            mx[f][r] = m;
        }
    if (col == 0) {
        #pragma unroll
        for (int f = 0; f < 2; ++f)
            #pragma unroll
            for (int r = 0; r < 4; ++r)
                red[0][f * 16 + quad * 4 + r][w] = mx[f][r];
    }
    __syncthreads();
    float sm[2][4];
    #pragma unroll
    for (int f = 0; f < 2; ++f)
        #pragma unroll
        for (int r = 0; r < 4; ++r) {
            const int row = f * 16 + quad * 4 + r;
            float m = red[0][row][0];
            #pragma unroll
            for (int t = 1; t < 8; ++t) m = fmaxf(m, red[0][row][t]);
            float s = 0.f;
            #pragma unroll
            for (int g = 0; g < 4; ++g) {
                const float e = __expf((acc[f][g][r] - m) * ATTN_SCALE);
                acc[f][g][r] = e;
                s += e;
            }
            #pragma unroll
            for (int t = 1; t < 16; t <<= 1) s += __shfl_xor(s, t);
            sm[f][r] = s;
        }
    if (col == 0) {
        #pragma unroll
        for (int f = 0; f < 2; ++f)
            #pragma unroll
            for (int r = 0; r < 4; ++r)
                red[1][f * 16 + quad * 4 + r][w] = sm[f][r];
    }
    __syncthreads();
    #pragma unroll
    for (int f = 0; f < 2; ++f)
        #pragma unroll
        for (int r = 0; r < 4; ++r) {
            const int row = f * 16 + quad * 4 + r;
            float tot = red[1][row][0];
            #pragma unroll
            for (int t = 1; t < 8; ++t) tot += red[1][row][t];
            const float inv = 1.f / tot;
            // frag-linear: c = w*64+g*16+col ->
            //   Pl[(f*16 + w*2+(g>>1))*512 + ((g&1)*2+(col>>3))*128
            //      + (quad*4+r)*8 + (col&7)]
            #pragma unroll
            for (int g = 0; g < 4; ++g)
                Pl[(f * 16 + w * 2 + (g >> 1)) * 512
                   + ((g & 1) * 2 + (col >> 3)) * 128
                   + (quad * 4 + r) * 8 + (col & 7)] =
                    f2bf(acc[f][g][r] * inv);
        }
    __syncthreads();   // Pl complete

    // ---- PV: out[32][1024] = P . V' ; wave w owns e = w*128..+128 ----
    // A-frags lane-linear from Pl (conflict-free); V double-buffered.
    f32x4 accp[2][8];
    #pragma unroll
    for (int f = 0; f < 2; ++f)
        #pragma unroll
        for (int g2 = 0; g2 < 8; ++g2) accp[f][g2] = z4;

    #pragma unroll
    for (int Kc = 0; Kc < 16; Kc += 2) {
        #pragma unroll
        for (int g2 = 0; g2 < 8; ++g2)
            bvB[g2] = *(const short8*)&Vz[(size_t)((w * 8 + g2) * 32 + Kc + 1) * 512
                                          + lane * 8];
        {
            const short8 a0 = *(const short8*)&Pl[Kc * 512 + lane * 8];
            const short8 a1 = *(const short8*)&Pl[(16 + Kc) * 512 + lane * 8];
            #pragma unroll
            for (int g2 = 0; g2 < 8; ++g2) {
                accp[0][g2] = __builtin_amdgcn_mfma_f32_16x16x32_bf16(
                    a0, bvA[g2], accp[0][g2], 0, 0, 0);
                accp[1][g2] = __builtin_amdgcn_mfma_f32_16x16x32_bf16(
                    a1, bvA[g2], accp[1][g2], 0, 0, 0);
            }
        }
        if (Kc + 2 < 16) {
            #pragma unroll
            for (int g2 = 0; g2 < 8; ++g2)
                bvA[g2] = *(const short8*)&Vz[(size_t)((w * 8 + g2) * 32 + Kc + 2) * 512
                                              + lane * 8];
        }
        {
            const short8 a2 = *(const short8*)&Pl[(Kc + 1) * 512 + lane * 8];
            const short8 a3 = *(const short8*)&Pl[(16 + Kc + 1) * 512 + lane * 8];
            #pragma unroll
            for (int g2 = 0; g2 < 8; ++g2) {
                accp[0][g2] = __builtin_amdgcn_mfma_f32_16x16x32_bf16(
                    a2, bvB[g2], accp[0][g2], 0, 0, 0);
                accp[1][g2] = __builtin_amdgcn_mfma_f32_16x16x32_bf16(
                    a3, bvB[g2], accp[1][g2], 0, 0, 0);
            }
        }
    }
    __syncthreads();   // done reading Pl; safe to overwrite as Ol

    // ---- epilogue: 2 halves (e<512 by waves 0-3, e>=512 by waves 4-7) ----
    // yT[n][cdim]: n = (e&7)*512 + qsem, cdim = hh*128 + (e>>3);
    // qsem = (rg&3)*128 + 4*rl + (rg>>2)   (stored-row un-permute)
    unsigned short* Ol = Pl;
    const int rl = tid >> 4, s8 = (tid >> 1) & 7, hw = tid & 1;
    const int qsem = ((rg & 3) << 7) + 4 * rl + (rg >> 2);
    const size_t nbase = (size_t)(s8 * 512 + qsem) * 512 + hh * 128;
    #pragma unroll
    for (int h2 = 0; h2 < 2; ++h2) {
        if ((w >> 2) == h2) {
            const int wl = w & 3;
            #pragma unroll
            for (int f = 0; f < 2; ++f)
                #pragma unroll
                for (int g2 = 0; g2 < 8; ++g2)
                    #pragma unroll
                    for (int r = 0; r < 4; ++r)
                        Ol[(f * 16 + quad * 4 + r) * 520
                           + wl * 128 + g2 * 16 + col] = f2bf(accp[f][g2][r]);
        }
        __syncthreads();
        #pragma unroll
        for (int v2 = 0; v2 < 4; ++v2) {
            const int cdb = hw * 32 + v2 * 8;
            unsigned int p[4];
            #pragma unroll
            for (int t = 0; t < 4; ++t) {
                const unsigned int a  = Ol[rl * 520 + s8 + 8 * (cdb + 2 * t)];
                const unsigned int bb = Ol[rl * 520 + s8 + 8 * (cdb + 2 * t + 1)];
                p[t] = a | (bb << 16);
            }
            uint4 o; o.x = p[0]; o.y = p[1]; o.z = p[2]; o.w = p[3];
            *(uint4*)&yTb[nbase + h2 * 64 + cdb] = o;
        }
        __syncthreads();
    }
}

// ---- K5: out = Wproj @ y + bias + x (NT vs yT), fp32 out ----
__global__ __launch_bounds__(256)
void gemm_proj(const unsigned short* __restrict__ Wpb,
               const unsigned short* __restrict__ yT,
               const float* __restrict__ bias, const float* __restrict__ x,
               float* __restrict__ out)
{
    __shared__ unsigned short sA[2 * 128 * 32], sB[2 * 128 * 32];
    const int b = blockIdx.z;
    const unsigned short* B = yT + (size_t)b * 2097152;  // [4096][512]
    const int m0 = blockIdx.y * 128, n0 = blockIdx.x * 128;

    f32x4 z4 = {0.f, 0.f, 0.f, 0.f};
    f32x4 acc[4][4];
    #pragma unroll
    for (int i = 0; i < 4; ++i)
        #pragma unroll
        for (int j = 0; j < 4; ++j) acc[i][j] = z4;

    mfma_core<512, 512, 512>(Wpb, B, m0, n0, sA, sB, acc);

    const int lane = threadIdx.x & 63, wave = threadIdx.x >> 6;
    const int wm = (wave & 1) * 64, wn = (wave >> 1) * 64;
    const int col = lane & 15, quad = lane >> 4;
    const size_t boff = (size_t)b * 2097152;
    #pragma unroll
    for (int i = 0; i < 4; ++i)
        #pragma unroll
        for (int r = 0; r < 4; ++r) {
            const int row = m0 + wm + i * 16 + quad * 4 + r;
            const float bi = bias[row];
            #pragma unroll
            for (int j = 0; j < 4; ++j) {
                const size_t idx = boff + (size_t)row * 4096 + n0 + wn + j * 16 + col;
                out[idx] = acc[i][j][r] + bi + x[idx];
            }
        }
}

extern "C" void kernel_launch(void* const* d_in, const int* in_sizes, int n_in,
                              void* d_out, int out_size, void* d_ws, size_t ws_size,
                              hipStream_t stream) {
    const float* x     = (const float*)d_in[0];
    const float* Wq    = (const float*)d_in[1];
    const float* Wk    = (const float*)d_in[2];
    const float* Wv    = (const float*)d_in[3];
    const float* Wproj = (const float*)d_in[4];
    const float* bproj = (const float*)d_in[5];
    float* out = (float*)d_out;

    char* w = (char*)d_ws;
    unsigned short* xT = (unsigned short*)(w + 0);          // 16 MB [b][n][c]
    unsigned short* qb = (unsigned short*)(w + 16777216);   // 16 MB frag-layout
    unsigned short* kb = (unsigned short*)(w + 33554432);   // 16 MB frag-layout
    unsigned short* vT = (unsigned short*)(w + 50331648);   // 16 MB frag-layout
    unsigned short* Wb = (unsigned short*)(w + 109051904);  //  2 MB
    unsigned short* yT = xT;   // xT dead after gemm_qkv

    prep        <<<dim3(64, 16, 5),  256, 0, stream>>>(x, Wq, Wk, Wv, Wproj, xT, Wb);
    gemm_qkv    <<<dim3(32, 4, 12),  256, 0, stream>>>(Wb, xT, qb, kb, vT);
    attn        <<<dim3(256),        512, 0, stream>>>(qb, kb, vT, yT);
    gemm_proj   <<<dim3(32, 4, 4),   256, 0, stream>>>(Wb + 3 * 262144, yT, bproj, x, out);
}

// Round 11
// 184.808 us; speedup vs baseline: 1.0423x; 1.0240x over previous
//
#include <hip/hip_runtime.h>
#include <stdint.h>

// SelfCrossAttn bf16-MFMA pipeline v16 == v13/v10 byte-identical revert.
// Best verified configuration: 185.7us (R5) / 186.1us (R8, different
// container). The v14/v15 qks+pv fusion arc regressed (192.6/189.2) and is
// abandoned; this closes on the known-best state.
// All GEMMs NT: C[m][n] = sum_k A[m][k]*B[n][k], operands k-contiguous.
// STORED row/col order for S/P and vT cols is kk'' = s*128+t (s = n>>10,
// t = ch&127); semantic attn index is 4t+s.  Sum over kk order-agnostic;
// P rows un-permuted only at gemm_pv's yT scatter.
//  prep    : W* fp32->bf16 (Wb) ; x[b][c][n] -> xT[b][n][c] bf16
//  gemm_qkv: v6 128^2 2-phase core (at the 613TF 2-phase ceiling).
//            Epilogues via LDS repack: q/k -> FRAGMENT-LINEAR layout,
//            V -> vT'[slab][e][kk''], all global stores b128 coalesced.
//  gemm_qks: fused S=Q.K^T (K=1024) + row softmax -> P bf16 (stored rows).
//            Register-direct coalesced frag loads, no LDS, no K barriers.
//  gemm_pv : O = P.V' ; un-permute rows into yT[n][c]
//  gemm_proj: out = Wproj @ y + bias + x (NT vs yT), fp32 (near HBM roofline)

typedef __attribute__((ext_vector_type(8))) short short8;
typedef __attribute__((ext_vector_type(4))) float f32x4;

typedef const __attribute__((address_space(1))) unsigned int* gas_ptr;
typedef __attribute__((address_space(3))) unsigned int* las_ptr;

#define ATTN_SCALE 0.08838834764831845f   // 128^-0.5

__device__ __forceinline__ unsigned short f2bf(float f) {
    union { float f; unsigned int u; } c; c.f = f;
    unsigned int u = c.u;
    u += 0x7fffu + ((u >> 16) & 1u);      // RNE
    return (unsigned short)(u >> 16);
}

__device__ __forceinline__ void gl_lds16(const void* g, void* l) {
    __builtin_amdgcn_global_load_lds((gas_ptr)(uintptr_t)g, (las_ptr)(uintptr_t)l,
                                     16, 0, 0);
}

// ---- v6 shared MFMA core: 128x128 C-tile, 4 waves, BK=32, 16x16x32 bf16 ----
template<int LDA, int LDB, int KDIM, bool PERMB = false>
__device__ __forceinline__ void mfma_core(
    const unsigned short* __restrict__ A,
    const unsigned short* __restrict__ B,
    int m0, int n0,
    unsigned short* __restrict__ sA, unsigned short* __restrict__ sB,
    f32x4 acc[4][4])
{
    const int tid  = threadIdx.x;
    const int lane = tid & 63, wave = tid >> 6;
    const int lr = lane >> 2, lc = lane & 3;       // staging: 16 rows x 4 chunks
    const int lcs = lc ^ ((lr >> 1) & 3);          // source-chunk swizzle
    const int wm = (wave & 1) * 64, wn = (wave >> 1) * 64;
    const int col = lane & 15, quad = lane >> 4;
    const int swz = (quad ^ ((col >> 1) & 3)) * 8; // read-side swizzle (shorts)

    const unsigned short* ga = A + (size_t)(m0 + 32 * wave + lr) * LDA + lcs * 8;
    int rb0 = n0 + 32 * wave + lr;
    int rb1 = rb0 + 16;
    if (PERMB) {
        rb0 = 4 * (rb0 & 127) + (rb0 >> 7);
        rb1 = 4 * (rb1 & 127) + (rb1 >> 7);
    }
    const unsigned short* gb0 = B + (size_t)rb0 * LDB + lcs * 8;
    const unsigned short* gb1 = B + (size_t)rb1 * LDB + lcs * 8;

    const int wr0 = (32 * wave) * 32;              // wave-uniform LDS row bases
    const int wr1 = (32 * wave + 16) * 32;

    // prologue: stage K-step 0 into buffer 0
    gl_lds16(ga,            sA + wr0);
    gl_lds16(ga + 16 * LDA, sA + wr1);
    gl_lds16(gb0,           sB + wr0);
    gl_lds16(gb1,           sB + wr1);

    constexpr int NK = KDIM / 32;
    for (int kk = 0; kk < NK; ++kk) {
        const int bo = (kk & 1) * 4096;
        if (kk + 1 < NK) {
            const int nb = ((kk + 1) & 1) * 4096;
            const int k0 = (kk + 1) * 32;
            gl_lds16(ga + k0,            sA + nb + wr0);
            gl_lds16(ga + k0 + 16 * LDA, sA + nb + wr1);
            gl_lds16(gb0 + k0,           sB + nb + wr0);
            gl_lds16(gb1 + k0,           sB + nb + wr1);
            asm volatile("s_waitcnt vmcnt(4)" ::: "memory");
        } else {
            asm volatile("s_waitcnt vmcnt(0)" ::: "memory");
        }
        __builtin_amdgcn_s_barrier();
        asm volatile("" ::: "memory");
        __builtin_amdgcn_sched_barrier(0);

        const unsigned short* bA = sA + bo;
        const unsigned short* bB = sB + bo;
        short8 af[4], bfv[4];
        #pragma unroll
        for (int i = 0; i < 4; ++i)
            af[i] = *(const short8*)&bA[(wm + i * 16 + col) * 32 + swz];
        #pragma unroll
        for (int j = 0; j < 4; ++j)
            bfv[j] = *(const short8*)&bB[(wn + j * 16 + col) * 32 + swz];
        #pragma unroll
        for (int i = 0; i < 4; ++i)
            #pragma unroll
            for (int j = 0; j < 4; ++j)
                acc[i][j] = __builtin_amdgcn_mfma_f32_16x16x32_bf16(
                    af[i], bfv[j], acc[i][j], 0, 0, 0);

        __builtin_amdgcn_s_barrier();          // reads done before next stage
        asm volatile("" ::: "memory");
    }
}

// ---- prep: z<4 -> transpose x[b][c][n]->xT[b][n][c] bf16 ; z==4 -> W conv ----
__global__ __launch_bounds__(256)
void prep(const float* __restrict__ x,
          const float* __restrict__ Wq, const float* __restrict__ Wk,
          const float* __restrict__ Wv, const float* __restrict__ Wp,
          unsigned short* __restrict__ xT, unsigned short* __restrict__ Wb)
{
    if (blockIdx.z == 4) {
        const int idx = (blockIdx.y * 64 + blockIdx.x) * 256 + threadIdx.x; // 262144
        const int mat = idx >> 16;
        const int off = (idx & 65535) << 2;
        const float* src = (mat == 0 ? Wq : mat == 1 ? Wk : mat == 2 ? Wv : Wp) + off;
        const float4 f = *(const float4*)src;
        uint2 o;
        o.x = f2bf(f.x) | ((unsigned)f2bf(f.y) << 16);
        o.y = f2bf(f.z) | ((unsigned)f2bf(f.w) << 16);
        *(uint2*)&Wb[mat * 262144 + off] = o;
        return;
    }
    const int b = blockIdx.z;
    const int l = threadIdx.x & 63, w = threadIdx.x >> 6;
    const int n  = blockIdx.x * 64 + l;
    const int c0 = blockIdx.y * 32 + w * 8;
    const float* xp = x + (size_t)b * 2097152 + (size_t)c0 * 4096 + n;
    unsigned int p[4];
    #pragma unroll
    for (int j = 0; j < 4; ++j) {
        const unsigned short a  = f2bf(xp[(2 * j)     * 4096]);
        const unsigned short bb = f2bf(xp[(2 * j + 1) * 4096]);
        p[j] = a | ((unsigned)bb << 16);
    }
    uint4 v; v.x = p[0]; v.y = p[1]; v.z = p[2]; v.w = p[3];
    *(uint4*)&xT[(size_t)b * 2097152 + (size_t)n * 512 + c0] = v;
}

// ---- K1: q/k = W @ x -> frag-linear (stored rows); V -> vT'[e][kk''] ----
__global__ __launch_bounds__(256)
void gemm_qkv(const unsigned short* __restrict__ Wb,
              const unsigned short* __restrict__ xT,
              unsigned short* __restrict__ qb, unsigned short* __restrict__ kb,
              unsigned short* __restrict__ vT)
{
    __shared__ unsigned short sT[128 * 136];          // 34.8 KB, aliases staging
    unsigned short* sA = sT;                          // [2][128*32] = 8192
    unsigned short* sB = sT + 8192;                   // [2][128*32] = 8192

    const int z = blockIdx.z, wsel = z >> 2, b = z & 3;
    const unsigned short* A = Wb + wsel * 262144;
    const unsigned short* B = xT + (size_t)b * 2097152;
    const int m0 = blockIdx.y * 128, n0 = blockIdx.x * 128;

    f32x4 z4 = {0.f, 0.f, 0.f, 0.f};
    f32x4 acc[4][4];
    #pragma unroll
    for (int i = 0; i < 4; ++i)
        #pragma unroll
        for (int j = 0; j < 4; ++j) acc[i][j] = z4;

    mfma_core<512, 512, 512>(A, B, m0, n0, sA, sB, acc);

    __syncthreads();   // drain before overwriting aliased staging

    const int tid = threadIdx.x;
    const int lane = tid & 63, wave = tid >> 6;
    const int wm = (wave & 1) * 64, wn = (wave >> 1) * 64;
    const int col = lane & 15, quad = lane >> 4;
    const int h = m0 >> 7, s = n0 >> 10;

    if (wsel < 2) {
        // stage C-tile [rr][ee], pad 136
        #pragma unroll
        for (int i = 0; i < 4; ++i)
            #pragma unroll
            for (int r = 0; r < 4; ++r) {
                const int rr = wm + i * 16 + quad * 4 + r;
                #pragma unroll
                for (int j = 0; j < 4; ++j)
                    sT[rr * 136 + wn + j * 16 + col] = f2bf(acc[i][j][r]);
            }
        __syncthreads();
        // frag-linear: stored_row = s*128 + t (t = rr); for elem (t, e):
        // addr = ((s*8 + t>>4)*32 + e>>5)*512 + (((e>>3)&3)*16 + (t&15))*8 + (e&7)
        unsigned short* C = (wsel == 0 ? qb : kb)
                          + (size_t)(b * 4 + h) * 524288;
        const int bKc = (n0 & 1023) >> 5;
        const int u = tid & 15, v = (tid >> 4) & 3, wv = tid >> 6;
        unsigned short* dst = C + (size_t)(s * 256 + bKc + wv) * 512
                            + (v * 16 + u) * 8;
        const unsigned short* src = sT + u * 136 + wv * 32 + v * 8;
        #pragma unroll
        for (int k = 0; k < 8; ++k)
            *(uint4*)(dst + k * 16384) = *(const uint4*)(src + k * 2176);
    } else {
        // stage transposed [ee][rr] (vT col kk'' = s*128 + rr), pad 136
        #pragma unroll
        for (int i = 0; i < 4; ++i)
            #pragma unroll
            for (int r = 0; r < 4; ++r) {
                const int rr = wm + i * 16 + quad * 4 + r;
                #pragma unroll
                for (int j = 0; j < 4; ++j)
                    sT[(wn + j * 16 + col) * 136 + rr] = f2bf(acc[i][j][r]);
            }
        __syncthreads();
        const int e0 = n0 & 1023;
        unsigned short* dst = vT + (size_t)(b * 4 + h) * 524288 + s * 128;
        const int u = tid & 15, rsel = tid >> 4;
        #pragma unroll
        for (int k = 0; k < 8; ++k) {
            const int ee = rsel + k * 16;
            *(uint4*)&dst[(size_t)(e0 + ee) * 512 + u * 8] =
                *(const uint4*)&sT[ee * 136 + u * 8];
        }
    }
}

// ---- K2: fused S = Q.K^T (K=1024) + row softmax -> P bf16 (stored rows) ----
__global__ __launch_bounds__(512)
void gemm_qks(const unsigned short* __restrict__ qb,
              const unsigned short* __restrict__ kb,
              unsigned short* __restrict__ P)
{
    __shared__ float red[2][32][8];
    const int d = blockIdx.x;                         // 0..255
    const int flat = (d & 7) * 32 + (d >> 3);         // XCD-chunked remap
    const int rg = flat & 15, z = flat >> 4;          // row-group, slab
    const unsigned short* Aq = qb + (size_t)z * 524288;
    const unsigned short* Bk = kb + (size_t)z * 524288;
    unsigned short* Pz = P + (size_t)z * 262144;

    const int tid = threadIdx.x;
    const int lane = tid & 63, w = tid >> 6;
    const int col = lane & 15, quad = lane >> 4;

    const unsigned short* ap0 = Aq + (size_t)((rg * 2 + 0) * 32) * 512 + lane * 8;
    const unsigned short* ap1 = Aq + (size_t)((rg * 2 + 1) * 32) * 512 + lane * 8;
    const unsigned short* bp0 = Bk + (size_t)((w * 4 + 0) * 32) * 512 + lane * 8;
    const unsigned short* bp1 = bp0 + 16384;
    const unsigned short* bp2 = bp0 + 32768;
    const unsigned short* bp3 = bp0 + 49152;

    f32x4 z4 = {0.f, 0.f, 0.f, 0.f};
    f32x4 acc[2][4];
    #pragma unroll
    for (int f = 0; f < 2; ++f)
        #pragma unroll
        for (int g = 0; g < 4; ++g) acc[f][g] = z4;

    #pragma unroll 4
    for (int kk = 0; kk < 32; ++kk) {
        const int o = kk * 512;
        const short8 af0 = *(const short8*)(ap0 + o);
        const short8 af1 = *(const short8*)(ap1 + o);
        short8 bf[4];
        bf[0] = *(const short8*)(bp0 + o);
        bf[1] = *(const short8*)(bp1 + o);
        bf[2] = *(const short8*)(bp2 + o);
        bf[3] = *(const short8*)(bp3 + o);
        #pragma unroll
        for (int g = 0; g < 4; ++g)
            acc[0][g] = __builtin_amdgcn_mfma_f32_16x16x32_bf16(
                af0, bf[g], acc[0][g], 0, 0, 0);
        #pragma unroll
        for (int g = 0; g < 4; ++g)
            acc[1][g] = __builtin_amdgcn_mfma_f32_16x16x32_bf16(
                af1, bf[g], acc[1][g], 0, 0, 0);
    }

    // ---- fused softmax over full 512-wide rows ----
    float mx[2][4];
    #pragma unroll
    for (int f = 0; f < 2; ++f)
        #pragma unroll
        for (int r = 0; r < 4; ++r) {
            float m = acc[f][0][r];
            #pragma unroll
            for (int g = 1; g < 4; ++g) m = fmaxf(m, acc[f][g][r]);
            #pragma unroll
            for (int s = 1; s < 16; s <<= 1) m = fmaxf(m, __shfl_xor(m, s));
            mx[f][r] = m;
        }
    if (col == 0) {
        #pragma unroll
        for (int f = 0; f < 2; ++f)
            #pragma unroll
            for (int r = 0; r < 4; ++r)
                red[0][f * 16 + quad * 4 + r][w] = mx[f][r];
    }
    __syncthreads();
    float sm[2][4];
    #pragma unroll
    for (int f = 0; f < 2; ++f)
        #pragma unroll
        for (int r = 0; r < 4; ++r) {
            const int row = f * 16 + quad * 4 + r;
            float m = red[0][row][0];
            #pragma unroll
            for (int t = 1; t < 8; ++t) m = fmaxf(m, red[0][row][t]);
            float s = 0.f;
            #pragma unroll
            for (int g = 0; g < 4; ++g) {
                const float e = __expf((acc[f][g][r] - m) * ATTN_SCALE);
                acc[f][g][r] = e;
                s += e;
            }
            #pragma unroll
            for (int t = 1; t < 16; t <<= 1) s += __shfl_xor(s, t);
            sm[f][r] = s;
        }
    if (col == 0) {
        #pragma unroll
        for (int f = 0; f < 2; ++f)
            #pragma unroll
            for (int r = 0; r < 4; ++r)
                red[1][f * 16 + quad * 4 + r][w] = sm[f][r];
    }
    __syncthreads();
    #pragma unroll
    for (int f = 0; f < 2; ++f)
        #pragma unroll
        for (int r = 0; r < 4; ++r) {
            const int row = f * 16 + quad * 4 + r;
            float tot = red[1][row][0];
            #pragma unroll
            for (int t = 1; t < 8; ++t) tot += red[1][row][t];
            const float inv = 1.f / tot;
            unsigned short* op = Pz + (size_t)(rg * 32 + row) * 512
                               + w * 64 + col;
            #pragma unroll
            for (int g = 0; g < 4; ++g)
                op[g * 16] = f2bf(acc[f][g][r] * inv);
        }
}

// ---- K4: O = P V' per slab; un-permute rows, scatter into yT[n][c] ----
__global__ __launch_bounds__(256)
void gemm_pv(const unsigned short* __restrict__ Pb,
             const unsigned short* __restrict__ vT,
             unsigned short* __restrict__ yT)
{
    __shared__ unsigned short sT[128 * 136];          // 34816 B; aliases staging
    unsigned short* sA = sT;                          // [2][128*32] = 8192
    unsigned short* sB = sT + 8192;                   // [2][128*32] = 8192
    const int z = blockIdx.z, b = z >> 2, hh = z & 3;
    const unsigned short* A = Pb + (size_t)z * 262144;   // [512][512] stored rows
    const unsigned short* B = vT + (size_t)z * 524288;   // [1024][512] kk''-rows
    unsigned short* yTb = yT + (size_t)b * 2097152;
    const int m0 = blockIdx.y * 128;   // stored-row block (fixed s_blk = m0>>7)
    const int n0 = blockIdx.x * 128;   // e

    f32x4 z4 = {0.f, 0.f, 0.f, 0.f};
    f32x4 acc[4][4];
    #pragma unroll
    for (int i = 0; i < 4; ++i)
        #pragma unroll
        for (int j = 0; j < 4; ++j) acc[i][j] = z4;

    mfma_core<512, 512, 512>(A, B, m0, n0, sA, sB, acc);

    // full drain before overwriting the aliased staging buffers with D-tile
    __syncthreads();

    const int tid = threadIdx.x;
    const int lane = tid & 63, wave = tid >> 6;
    const int wm = (wave & 1) * 64, wn = (wave >> 1) * 64;
    const int col = lane & 15, quad = lane >> 4;

    // D tile -> LDS [stored-row local][e_local], pad 136
    #pragma unroll
    for (int i = 0; i < 4; ++i)
        #pragma unroll
        for (int r = 0; r < 4; ++r) {
            const int rr = wm + i * 16 + quad * 4 + r;
            #pragma unroll
            for (int j = 0; j < 4; ++j)
                sT[rr * 136 + wn + j * 16 + col] = f2bf(acc[i][j][r]);
        }
    __syncthreads();

    // pack 16-elem c-runs; stored row m0+qq_l -> actual qq = 4*qq_l + (m0>>7)
    const int sblk = m0 >> 7;
    #pragma unroll
    for (int k = 0; k < 4; ++k) {
        const int rid = k * 256 + tid;       // 0..1023
        const int qq_l = rid >> 3, s = rid & 7;
        const unsigned short* Trow = sT + qq_l * 136;
        unsigned int p[8];
        #pragma unroll
        for (int t = 0; t < 8; ++t) {
            const unsigned int a  = Trow[s + 8 * (2 * t)];
            const unsigned int bb = Trow[s + 8 * (2 * t + 1)];
            p[t] = a | (bb << 16);
        }
        const size_t base = (size_t)((s << 9) + 4 * qq_l + sblk) * 512
                          + hh * 128 + (n0 >> 3);
        uint4 lo; lo.x = p[0]; lo.y = p[1]; lo.z = p[2]; lo.w = p[3];
        uint4 hi; hi.x = p[4]; hi.y = p[5]; hi.z = p[6]; hi.w = p[7];
        *(uint4*)&yTb[base]     = lo;
        *(uint4*)&yTb[base + 8] = hi;
    }
}

// ---- K5: out = Wproj @ y + bias + x (NT vs yT), fp32 out ----
__global__ __launch_bounds__(256)
void gemm_proj(const unsigned short* __restrict__ Wpb,
               const unsigned short* __restrict__ yT,
               const float* __restrict__ bias, const float* __restrict__ x,
               float* __restrict__ out)
{
    __shared__ unsigned short sA[2 * 128 * 32], sB[2 * 128 * 32];
    const int b = blockIdx.z;
    const unsigned short* B = yT + (size_t)b * 2097152;  // [4096][512]
    const int m0 = blockIdx.y * 128, n0 = blockIdx.x * 128;

    f32x4 z4 = {0.f, 0.f, 0.f, 0.f};
    f32x4 acc[4][4];
    #pragma unroll
    for (int i = 0; i < 4; ++i)
        #pragma unroll
        for (int j = 0; j < 4; ++j) acc[i][j] = z4;

    mfma_core<512, 512, 512>(Wpb, B, m0, n0, sA, sB, acc);

    const int lane = threadIdx.x & 63, wave = threadIdx.x >> 6;
    const int wm = (wave & 1) * 64, wn = (wave >> 1) * 64;
    const int col = lane & 15, quad = lane >> 4;
    const size_t boff = (size_t)b * 2097152;
    #pragma unroll
    for (int i = 0; i < 4; ++i)
        #pragma unroll
        for (int r = 0; r < 4; ++r) {
            const int row = m0 + wm + i * 16 + quad * 4 + r;
            const float bi = bias[row];
            #pragma unroll
            for (int j = 0; j < 4; ++j) {
                const size_t idx = boff + (size_t)row * 4096 + n0 + wn + j * 16 + col;
                out[idx] = acc[i][j][r] + bi + x[idx];
            }
        }
}

extern "C" void kernel_launch(void* const* d_in, const int* in_sizes, int n_in,
                              void* d_out, int out_size, void* d_ws, size_t ws_size,
                              hipStream_t stream) {
    const float* x     = (const float*)d_in[0];
    const float* Wq    = (const float*)d_in[1];
    const float* Wk    = (const float*)d_in[2];
    const float* Wv    = (const float*)d_in[3];
    const float* Wproj = (const float*)d_in[4];
    const float* bproj = (const float*)d_in[5];
    float* out = (float*)d_out;

    char* w = (char*)d_ws;
    unsigned short* xT = (unsigned short*)(w + 0);          // 16 MB [b][n][c]
    unsigned short* qb = (unsigned short*)(w + 16777216);   // 16 MB frag-layout
    unsigned short* kb = (unsigned short*)(w + 33554432);   // 16 MB frag-layout
    unsigned short* vT = (unsigned short*)(w + 50331648);   // 16 MB [slab][e][kk'']
    unsigned short* Pb = (unsigned short*)(w + 100663296);  //  8 MB
    unsigned short* Wb = (unsigned short*)(w + 109051904);  //  2 MB
    unsigned short* yT = xT;   // xT dead after gemm_qkv

    prep        <<<dim3(64, 16, 5),  256, 0, stream>>>(x, Wq, Wk, Wv, Wproj, xT, Wb);
    gemm_qkv    <<<dim3(32, 4, 12),  256, 0, stream>>>(Wb, xT, qb, kb, vT);
    gemm_qks    <<<dim3(256),        512, 0, stream>>>(qb, kb, Pb);
    gemm_pv     <<<dim3(8, 4, 16),   256, 0, stream>>>(Pb, vT, yT);
    gemm_proj   <<<dim3(32, 4, 4),   256, 0, stream>>>(Wb + 3 * 262144, yT, bproj, x, out);
}